// Round 1
// baseline (71.895 us; speedup 1.0000x reference)
//
#include <hip/hip_runtime.h>

namespace {

constexpr int N  = 50000;
constexpr int R  = 10;
constexpr int DD = 5;
constexpr int RN = R * N;        // 500000
constexpr int DN = DD * N;       // 250000
constexpr int E  = 10000000;

// ---------------------------------------------------------------------------
// Kernel A: acc = inputs  (rec_inputs accumulator seeded with feedforward input)
__global__ __launch_bounds__(256) void init_acc_kernel(
    const float4* __restrict__ inputs, float4* __restrict__ acc, int n4)
{
    int i = blockIdx.x * 256 + threadIdx.x;
    if (i < n4) acc[i] = inputs[i];
}

// ---------------------------------------------------------------------------
// Kernel B: sparse scatter  acc[row[e]] += rec_w[e] * z[col[e]]
// z is 0/1 with ~2% density -> predicate the atomic (and the rec_w load).
__global__ __launch_bounds__(256) void scatter_kernel(
    const float* __restrict__ rec_w,
    const int2*  __restrict__ rec_idx,   // [e] = (row, col)
    const float* __restrict__ z,         // z_buf, DN elements, L2-resident (1 MB)
    float*       __restrict__ acc)
{
    int e = blockIdx.x * 256 + threadIdx.x;
    if (e >= E) return;
    int2 rc = rec_idx[e];
    float zc = z[rc.y];
    if (zc != 0.0f) {
        atomicAdd(acc + rc.x, rec_w[e] * zc);
    }
}

// ---------------------------------------------------------------------------
// Kernel C: synapse update (RN elements, float4-vectorized)
// new_psc_rise = syn_decay*psc_rise + acc*psc_initial
// new_psc      = psc*syn_decay + DT*syn_decay*psc_rise   (DT = 1)
__global__ __launch_bounds__(256) void syn_kernel(
    const float4* __restrict__ acc,
    const float4* __restrict__ psc_rise,
    const float4* __restrict__ psc,
    const float4* __restrict__ syn_decay,
    const float4* __restrict__ psc_initial,
    float4* __restrict__ out_psc_rise,
    float4* __restrict__ out_psc,
    int n4)
{
    int j = blockIdx.x * 256 + threadIdx.x;
    if (j >= n4) return;
    float4 sd = syn_decay[j];
    float4 pr = psc_rise[j];
    float4 pi = psc_initial[j];
    float4 ac = acc[j];
    float4 ps = psc[j];
    float4 opr, ops;
    opr.x = sd.x * pr.x + ac.x * pi.x;
    opr.y = sd.y * pr.y + ac.y * pi.y;
    opr.z = sd.z * pr.z + ac.z * pi.z;
    opr.w = sd.w * pr.w + ac.w * pi.w;
    ops.x = ps.x * sd.x + sd.x * pr.x;
    ops.y = ps.y * sd.y + sd.y * pr.y;
    ops.z = ps.z * sd.z + sd.z * pr.z;
    ops.w = ps.w * sd.w + sd.w * pr.w;
    out_psc_rise[j] = opr;
    out_psc[j]      = ops;
}

// ---------------------------------------------------------------------------
// Kernel D: per-neuron update (N elements)
__global__ __launch_bounds__(256) void neuron_kernel(
    const float*  __restrict__ z_buf,       // slot 0 = prev_z
    const float*  __restrict__ v,
    const float*  __restrict__ r,
    const float*  __restrict__ asc1,
    const float*  __restrict__ asc2,
    const float*  __restrict__ psc,          // OLD psc, summed over R per neuron
    const float*  __restrict__ v_th,
    const float*  __restrict__ e_l,
    const float*  __restrict__ v_reset,
    const float*  __restrict__ g,
    const float*  __restrict__ decay,
    const float*  __restrict__ current_factor,
    const float*  __restrict__ t_ref,
    const float2* __restrict__ k,            // (N,2)
    const float2* __restrict__ asc_amps,     // (N,2)
    const float*  __restrict__ voltage_scale,
    const float*  __restrict__ voltage_offset,
    float* __restrict__ out)
{
    int n = blockIdx.x * 256 + threadIdx.x;
    if (n >= N) return;

    float prev_z = z_buf[n];

    // input_current = sum_{rr} psc[n*R + rr]  (n*R is even -> float2-aligned)
    const float2* p2 = reinterpret_cast<const float2*>(psc + n * R);
    float ic = 0.0f;
#pragma unroll
    for (int t = 0; t < R / 2; ++t) {
        float2 p = p2[t];
        ic += p.x + p.y;
    }

    float new_r = fmaxf(r[n] + prev_z * t_ref[n] - 1.0f, 0.0f);   // DT = 1

    float2 kk = k[n];
    float2 aa = asc_amps[n];
    float s0 = 1.0f / (1.0f + expf(-kk.x));
    float s1 = 1.0f / (1.0f + expf(-kk.y));
    float a1_old = asc1[n];
    float a2_old = asc2[n];
    float new_a1 = expf(-s0) * a1_old + prev_z * aa.x;
    float new_a2 = expf(-s1) * a2_old + prev_z * aa.y;

    float el = e_l[n];
    float new_v = decay[n] * v[n]
                + current_factor[n] * (ic + a1_old + a2_old + g[n] * el);

    float vth = v_th[n];
    float v_sc = (new_v - vth) / (vth - el);
    float nz = (v_sc > 0.0f) ? 1.0f : 0.0f;
    if (new_r > 0.0f) nz = 0.0f;
    if (nz > 0.5f) new_v = v_reset[n];

    out[0 * N + n]  = nz;                                          // new_z
    out[1 * N + n]  = new_v * voltage_scale[n] + voltage_offset[n];// out_v
    out[2 * N + n]  = nz;                                          // z_buf slot 0
    out[7 * N + n]  = new_v;                                       // new_v
    out[8 * N + n]  = new_r;                                       // new_r
    out[9 * N + n]  = new_a1;                                      // new_asc_1
    out[10 * N + n] = new_a2;                                      // new_asc_2
}

// ---------------------------------------------------------------------------
// Kernel E: z_buf shift — out_zbuf[N : D*N] = z_buf[0 : (D-1)*N]
__global__ __launch_bounds__(256) void zbuf_shift_kernel(
    const float4* __restrict__ z_buf, float4* __restrict__ dst, int n4)
{
    int i = blockIdx.x * 256 + threadIdx.x;
    if (i < n4) dst[i] = z_buf[i];
}

} // namespace

extern "C" void kernel_launch(void* const* d_in, const int* in_sizes, int n_in,
                              void* d_out, int out_size, void* d_ws, size_t ws_size,
                              hipStream_t stream) {
    const float* inputs         = (const float*)d_in[0];
    const float* z_buf          = (const float*)d_in[1];
    const float* v              = (const float*)d_in[2];
    const float* r              = (const float*)d_in[3];
    const float* asc1           = (const float*)d_in[4];
    const float* asc2           = (const float*)d_in[5];
    const float* psc_rise       = (const float*)d_in[6];
    const float* psc            = (const float*)d_in[7];
    const float* rec_w          = (const float*)d_in[8];
    const int*   rec_idx        = (const int*)d_in[9];
    const float* v_th           = (const float*)d_in[10];
    const float* e_l            = (const float*)d_in[11];
    const float* v_reset        = (const float*)d_in[12];
    const float* g              = (const float*)d_in[13];
    const float* decay          = (const float*)d_in[14];
    const float* current_factor = (const float*)d_in[15];
    const float* t_ref          = (const float*)d_in[16];
    const float* k              = (const float*)d_in[17];
    const float* asc_amps       = (const float*)d_in[18];
    const float* syn_decay      = (const float*)d_in[19];
    const float* psc_initial    = (const float*)d_in[20];
    const float* voltage_scale  = (const float*)d_in[21];
    const float* voltage_offset = (const float*)d_in[22];

    float* out = (float*)d_out;
    float* acc = (float*)d_ws;   // RN floats = 2 MB scratch

    // A: seed accumulator with feedforward inputs
    init_acc_kernel<<<(RN / 4 + 255) / 256, 256, 0, stream>>>(
        (const float4*)inputs, (float4*)acc, RN / 4);

    // B: sparse recurrent scatter (dominant dispatch)
    scatter_kernel<<<(E + 255) / 256, 256, 0, stream>>>(
        rec_w, (const int2*)rec_idx, z_buf, acc);

    // D: neuron update (independent of scatter; uses OLD psc/asc)
    neuron_kernel<<<(N + 255) / 256, 256, 0, stream>>>(
        z_buf, v, r, asc1, asc2, psc, v_th, e_l, v_reset, g, decay,
        current_factor, t_ref, (const float2*)k, (const float2*)asc_amps,
        voltage_scale, voltage_offset, out);

    // E: shift delay buffer (out[2N..] slot 1..D-1 <- z_buf slot 0..D-2)
    zbuf_shift_kernel<<<((DN - N) / 4 + 255) / 256, 256, 0, stream>>>(
        (const float4*)z_buf, (float4*)(out + 3 * N), (DN - N) / 4);

    // C: synapse update (depends on scatter's acc)
    syn_kernel<<<(RN / 4 + 255) / 256, 256, 0, stream>>>(
        (const float4*)acc, (const float4*)psc_rise, (const float4*)psc,
        (const float4*)syn_decay, (const float4*)psc_initial,
        (float4*)(out + 11 * N), (float4*)(out + 21 * N), RN / 4);
}

// Round 2
// 43.546 us; speedup vs baseline: 1.6510x; 1.6510x over previous
//
#include <hip/hip_runtime.h>

namespace {

constexpr int N  = 50000;
constexpr int R  = 10;
constexpr int DD = 5;
constexpr int RN = R * N;        // 500000
constexpr int DN = DD * N;       // 250000
constexpr int E  = 10000000;
constexpr int EP = E / 2;        // edge pairs

// bitmask geometry: zbits kernel launches ceil-to-256 threads over DN bits
constexpr int ZB_BLOCKS = (DN + 255) / 256;          // 977
constexpr int ZB_WORDS  = ZB_BLOCKS * 256 / 32;      // 7816 u32 words (31264 B)

// ---------------------------------------------------------------------------
// Kernel A: acc = inputs  (rec_inputs accumulator seeded with feedforward input)
__global__ __launch_bounds__(256) void init_acc_kernel(
    const float4* __restrict__ inputs, float4* __restrict__ acc, int n4)
{
    int i = blockIdx.x * 256 + threadIdx.x;
    if (i < n4) acc[i] = inputs[i];
}

// ---------------------------------------------------------------------------
// Kernel Z: build spike bitmask  bits[w] holds z!=0 for columns [32w, 32w+32)
__global__ __launch_bounds__(256) void zbits_kernel(
    const float* __restrict__ z, unsigned int* __restrict__ bits)
{
    int i = blockIdx.x * 256 + threadIdx.x;
    float zv = (i < DN) ? z[i] : 0.0f;
    unsigned long long m = __ballot(zv != 0.0f);
    if ((threadIdx.x & 63) == 0) {
        int w = i >> 5;                       // i is a multiple of 64
        bits[w]     = (unsigned int)m;
        bits[w + 1] = (unsigned int)(m >> 32);
    }
}

// ---------------------------------------------------------------------------
// Kernel B: sparse scatter  acc[row] += rec_w[e]  iff bit(col) set.
// Bitmask staged in LDS; idx streamed as int4 (2 edges per load).
__global__ __launch_bounds__(256) void scatter_kernel(
    const float* __restrict__ rec_w,
    const int4*  __restrict__ idx4,          // [p] = (row0, col0, row1, col1)
    const unsigned int* __restrict__ bits_g,
    float*       __restrict__ acc)
{
    __shared__ unsigned int bits[ZB_WORDS];
    for (int i = threadIdx.x; i < ZB_WORDS; i += 256)
        bits[i] = bits_g[i];
    __syncthreads();

    int stride = gridDim.x * 256;
    for (int p = blockIdx.x * 256 + threadIdx.x; p < EP; p += stride) {
        int4 rc = idx4[p];
        unsigned int w0 = bits[rc.y >> 5];
        unsigned int w1 = bits[rc.w >> 5];
        if ((w0 >> (rc.y & 31)) & 1u) atomicAdd(acc + rc.x, rec_w[2 * p]);
        if ((w1 >> (rc.w & 31)) & 1u) atomicAdd(acc + rc.z, rec_w[2 * p + 1]);
    }
}

// ---------------------------------------------------------------------------
// Kernel C: synapse update (RN elements, float4-vectorized)
__global__ __launch_bounds__(256) void syn_kernel(
    const float4* __restrict__ acc,
    const float4* __restrict__ psc_rise,
    const float4* __restrict__ psc,
    const float4* __restrict__ syn_decay,
    const float4* __restrict__ psc_initial,
    float4* __restrict__ out_psc_rise,
    float4* __restrict__ out_psc,
    int n4)
{
    int j = blockIdx.x * 256 + threadIdx.x;
    if (j >= n4) return;
    float4 sd = syn_decay[j];
    float4 pr = psc_rise[j];
    float4 pi = psc_initial[j];
    float4 ac = acc[j];
    float4 ps = psc[j];
    float4 opr, ops;
    opr.x = sd.x * pr.x + ac.x * pi.x;
    opr.y = sd.y * pr.y + ac.y * pi.y;
    opr.z = sd.z * pr.z + ac.z * pi.z;
    opr.w = sd.w * pr.w + ac.w * pi.w;
    ops.x = ps.x * sd.x + sd.x * pr.x;
    ops.y = ps.y * sd.y + sd.y * pr.y;
    ops.z = ps.z * sd.z + sd.z * pr.z;
    ops.w = ps.w * sd.w + sd.w * pr.w;
    out_psc_rise[j] = opr;
    out_psc[j]      = ops;
}

// ---------------------------------------------------------------------------
// Kernel D: per-neuron update (N elements)
__global__ __launch_bounds__(256) void neuron_kernel(
    const float*  __restrict__ z_buf,       // slot 0 = prev_z
    const float*  __restrict__ v,
    const float*  __restrict__ r,
    const float*  __restrict__ asc1,
    const float*  __restrict__ asc2,
    const float*  __restrict__ psc,          // OLD psc, summed over R per neuron
    const float*  __restrict__ v_th,
    const float*  __restrict__ e_l,
    const float*  __restrict__ v_reset,
    const float*  __restrict__ g,
    const float*  __restrict__ decay,
    const float*  __restrict__ current_factor,
    const float*  __restrict__ t_ref,
    const float2* __restrict__ k,            // (N,2)
    const float2* __restrict__ asc_amps,     // (N,2)
    const float*  __restrict__ voltage_scale,
    const float*  __restrict__ voltage_offset,
    float* __restrict__ out)
{
    int n = blockIdx.x * 256 + threadIdx.x;
    if (n >= N) return;

    float prev_z = z_buf[n];

    const float2* p2 = reinterpret_cast<const float2*>(psc + n * R);
    float ic = 0.0f;
#pragma unroll
    for (int t = 0; t < R / 2; ++t) {
        float2 p = p2[t];
        ic += p.x + p.y;
    }

    float new_r = fmaxf(r[n] + prev_z * t_ref[n] - 1.0f, 0.0f);   // DT = 1

    float2 kk = k[n];
    float2 aa = asc_amps[n];
    float s0 = 1.0f / (1.0f + expf(-kk.x));
    float s1 = 1.0f / (1.0f + expf(-kk.y));
    float a1_old = asc1[n];
    float a2_old = asc2[n];
    float new_a1 = expf(-s0) * a1_old + prev_z * aa.x;
    float new_a2 = expf(-s1) * a2_old + prev_z * aa.y;

    float el = e_l[n];
    float new_v = decay[n] * v[n]
                + current_factor[n] * (ic + a1_old + a2_old + g[n] * el);

    float vth = v_th[n];
    float v_sc = (new_v - vth) / (vth - el);
    float nz = (v_sc > 0.0f) ? 1.0f : 0.0f;
    if (new_r > 0.0f) nz = 0.0f;
    if (nz > 0.5f) new_v = v_reset[n];

    out[0 * N + n]  = nz;                                          // new_z
    out[1 * N + n]  = new_v * voltage_scale[n] + voltage_offset[n];// out_v
    out[2 * N + n]  = nz;                                          // z_buf slot 0
    out[7 * N + n]  = new_v;                                       // new_v
    out[8 * N + n]  = new_r;                                       // new_r
    out[9 * N + n]  = new_a1;                                      // new_asc_1
    out[10 * N + n] = new_a2;                                      // new_asc_2
}

// ---------------------------------------------------------------------------
// Kernel E: z_buf shift — out_zbuf[N : D*N] = z_buf[0 : (D-1)*N]
__global__ __launch_bounds__(256) void zbuf_shift_kernel(
    const float4* __restrict__ z_buf, float4* __restrict__ dst, int n4)
{
    int i = blockIdx.x * 256 + threadIdx.x;
    if (i < n4) dst[i] = z_buf[i];
}

} // namespace

extern "C" void kernel_launch(void* const* d_in, const int* in_sizes, int n_in,
                              void* d_out, int out_size, void* d_ws, size_t ws_size,
                              hipStream_t stream) {
    const float* inputs         = (const float*)d_in[0];
    const float* z_buf          = (const float*)d_in[1];
    const float* v              = (const float*)d_in[2];
    const float* r              = (const float*)d_in[3];
    const float* asc1           = (const float*)d_in[4];
    const float* asc2           = (const float*)d_in[5];
    const float* psc_rise       = (const float*)d_in[6];
    const float* psc            = (const float*)d_in[7];
    const float* rec_w          = (const float*)d_in[8];
    const int*   rec_idx        = (const int*)d_in[9];
    const float* v_th           = (const float*)d_in[10];
    const float* e_l            = (const float*)d_in[11];
    const float* v_reset        = (const float*)d_in[12];
    const float* g              = (const float*)d_in[13];
    const float* decay          = (const float*)d_in[14];
    const float* current_factor = (const float*)d_in[15];
    const float* t_ref          = (const float*)d_in[16];
    const float* k              = (const float*)d_in[17];
    const float* asc_amps       = (const float*)d_in[18];
    const float* syn_decay      = (const float*)d_in[19];
    const float* psc_initial    = (const float*)d_in[20];
    const float* voltage_scale  = (const float*)d_in[21];
    const float* voltage_offset = (const float*)d_in[22];

    float* out = (float*)d_out;
    float* acc = (float*)d_ws;                         // RN floats = 2 MB
    unsigned int* bits = (unsigned int*)(acc + RN);    // ZB_WORDS u32 = 31 KB

    // Z: spike bitmask (needed by scatter)
    zbits_kernel<<<ZB_BLOCKS, 256, 0, stream>>>(z_buf, bits);

    // A: seed accumulator with feedforward inputs
    init_acc_kernel<<<(RN / 4 + 255) / 256, 256, 0, stream>>>(
        (const float4*)inputs, (float4*)acc, RN / 4);

    // B: sparse recurrent scatter (dominant dispatch)
    // 1280 blocks = 5 blocks/CU (31 KB LDS each) x 256 CUs, grid-stride.
    scatter_kernel<<<1280, 256, 0, stream>>>(
        rec_w, (const int4*)rec_idx, bits, acc);

    // D: neuron update (independent of scatter; uses OLD psc/asc)
    neuron_kernel<<<(N + 255) / 256, 256, 0, stream>>>(
        z_buf, v, r, asc1, asc2, psc, v_th, e_l, v_reset, g, decay,
        current_factor, t_ref, (const float2*)k, (const float2*)asc_amps,
        voltage_scale, voltage_offset, out);

    // E: shift delay buffer (out slot 1..D-1 <- z_buf slot 0..D-2)
    zbuf_shift_kernel<<<((DN - N) / 4 + 255) / 256, 256, 0, stream>>>(
        (const float4*)z_buf, (float4*)(out + 3 * N), (DN - N) / 4);

    // C: synapse update (depends on scatter's acc)
    syn_kernel<<<(RN / 4 + 255) / 256, 256, 0, stream>>>(
        (const float4*)acc, (const float4*)psc_rise, (const float4*)psc,
        (const float4*)syn_decay, (const float4*)psc_initial,
        (float4*)(out + 11 * N), (float4*)(out + 21 * N), RN / 4);
}

// Round 3
// 35.080 us; speedup vs baseline: 2.0495x; 1.2413x over previous
//
#include <hip/hip_runtime.h>

namespace {

constexpr int N  = 50000;
constexpr int R  = 10;
constexpr int DD = 5;
constexpr int RN = R * N;        // 500000
constexpr int DN = DD * N;       // 250000
constexpr int E  = 10000000;
constexpr int EP = E / 2;        // edge pairs

// bitmask geometry
constexpr int ZB_BLOCKS = (DN + 255) / 256;          // 977
constexpr int ZB_WORDS  = ZB_BLOCKS * 256 / 32;      // 7816 u32 (31264 B)

// fused pre-kernel block partition
constexpr int AC_BLOCKS   = (RN / 4 + 255) / 256;    // 489
constexpr int NEUR_BLOCKS = (N + 255) / 256;         // 196
constexpr int SH_BLOCKS   = ((DN - N) / 4 + 255) / 256; // 196
constexpr int PRE_BLOCKS  = ZB_BLOCKS + AC_BLOCKS + NEUR_BLOCKS + SH_BLOCKS;

// ---------------------------------------------------------------------------
// Fused pre-kernel: everything that does NOT depend on the scatter.
//  range 0: zbits   — spike bitmask from z_buf
//  range 1: init_acc — acc = inputs
//  range 2: neuron  — per-neuron state update (uses OLD psc/asc)
//  range 3: shift   — delay-buffer shift
__global__ __launch_bounds__(256) void pre_kernel(
    const float*  __restrict__ z_buf,
    unsigned int* __restrict__ bits,
    const float4* __restrict__ inputs,
    float4*       __restrict__ acc,
    const float*  __restrict__ v,
    const float*  __restrict__ r,
    const float*  __restrict__ asc1,
    const float*  __restrict__ asc2,
    const float*  __restrict__ psc,
    const float*  __restrict__ v_th,
    const float*  __restrict__ e_l,
    const float*  __restrict__ v_reset,
    const float*  __restrict__ g,
    const float*  __restrict__ decay,
    const float*  __restrict__ current_factor,
    const float*  __restrict__ t_ref,
    const float2* __restrict__ k,
    const float2* __restrict__ asc_amps,
    const float*  __restrict__ voltage_scale,
    const float*  __restrict__ voltage_offset,
    float*        __restrict__ out)
{
    int b = blockIdx.x;
    int tid = threadIdx.x;

    if (b < ZB_BLOCKS) {
        // ---- zbits ----
        int i = b * 256 + tid;
        float zv = (i < DN) ? z_buf[i] : 0.0f;
        unsigned long long m = __ballot(zv != 0.0f);
        if ((tid & 63) == 0) {
            int w = i >> 5;
            bits[w]     = (unsigned int)m;
            bits[w + 1] = (unsigned int)(m >> 32);
        }
        return;
    }
    b -= ZB_BLOCKS;
    if (b < AC_BLOCKS) {
        // ---- init_acc ----
        int i = b * 256 + tid;
        if (i < RN / 4) acc[i] = inputs[i];
        return;
    }
    b -= AC_BLOCKS;
    if (b < NEUR_BLOCKS) {
        // ---- neuron ----
        int n = b * 256 + tid;
        if (n >= N) return;

        float prev_z = z_buf[n];

        const float2* p2 = reinterpret_cast<const float2*>(psc + n * R);
        float ic = 0.0f;
#pragma unroll
        for (int t = 0; t < R / 2; ++t) {
            float2 p = p2[t];
            ic += p.x + p.y;
        }

        float new_r = fmaxf(r[n] + prev_z * t_ref[n] - 1.0f, 0.0f);   // DT=1

        float2 kk = k[n];
        float2 aa = asc_amps[n];
        float s0 = 1.0f / (1.0f + expf(-kk.x));
        float s1 = 1.0f / (1.0f + expf(-kk.y));
        float a1_old = asc1[n];
        float a2_old = asc2[n];
        float new_a1 = expf(-s0) * a1_old + prev_z * aa.x;
        float new_a2 = expf(-s1) * a2_old + prev_z * aa.y;

        float el = e_l[n];
        float new_v = decay[n] * v[n]
                    + current_factor[n] * (ic + a1_old + a2_old + g[n] * el);

        float vth = v_th[n];
        float v_sc = (new_v - vth) / (vth - el);
        float nz = (v_sc > 0.0f) ? 1.0f : 0.0f;
        if (new_r > 0.0f) nz = 0.0f;
        if (nz > 0.5f) new_v = v_reset[n];

        out[0 * N + n]  = nz;
        out[1 * N + n]  = new_v * voltage_scale[n] + voltage_offset[n];
        out[2 * N + n]  = nz;
        out[7 * N + n]  = new_v;
        out[8 * N + n]  = new_r;
        out[9 * N + n]  = new_a1;
        out[10 * N + n] = new_a2;
        return;
    }
    b -= NEUR_BLOCKS;
    {
        // ---- zbuf shift: out[3N ..] <- z_buf[0 .. DN-N) ----
        int i = b * 256 + tid;
        if (i < (DN - N) / 4) {
            const float4* src = reinterpret_cast<const float4*>(z_buf);
            float4* dst = reinterpret_cast<float4*>(out + 3 * N);
            dst[i] = src[i];
        }
        return;
    }
}

// ---------------------------------------------------------------------------
// Scatter: acc[row] += rec_w[e]  iff bit(col).  Bitmask in LDS; idx as int4;
// unroll x2 for memory-level parallelism.
__global__ __launch_bounds__(256) void scatter_kernel(
    const float* __restrict__ rec_w,
    const int4*  __restrict__ idx4,          // [p] = (row0, col0, row1, col1)
    const unsigned int* __restrict__ bits_g,
    float*       __restrict__ acc)
{
    __shared__ unsigned int bits[ZB_WORDS];
    for (int i = threadIdx.x; i < ZB_WORDS; i += 256)
        bits[i] = bits_g[i];
    __syncthreads();

    int stride = gridDim.x * 256;
    int p = blockIdx.x * 256 + threadIdx.x;
    for (; p + stride < EP; p += 2 * stride) {
        int4 a = idx4[p];
        int4 c = idx4[p + stride];
        unsigned int wa0 = bits[a.y >> 5];
        unsigned int wa1 = bits[a.w >> 5];
        unsigned int wc0 = bits[c.y >> 5];
        unsigned int wc1 = bits[c.w >> 5];
        if ((wa0 >> (a.y & 31)) & 1u) atomicAdd(acc + a.x, rec_w[2 * p]);
        if ((wa1 >> (a.w & 31)) & 1u) atomicAdd(acc + a.z, rec_w[2 * p + 1]);
        if ((wc0 >> (c.y & 31)) & 1u) atomicAdd(acc + c.x, rec_w[2 * (p + stride)]);
        if ((wc1 >> (c.w & 31)) & 1u) atomicAdd(acc + c.z, rec_w[2 * (p + stride) + 1]);
    }
    if (p < EP) {
        int4 a = idx4[p];
        unsigned int wa0 = bits[a.y >> 5];
        unsigned int wa1 = bits[a.w >> 5];
        if ((wa0 >> (a.y & 31)) & 1u) atomicAdd(acc + a.x, rec_w[2 * p]);
        if ((wa1 >> (a.w & 31)) & 1u) atomicAdd(acc + a.z, rec_w[2 * p + 1]);
    }
}

// ---------------------------------------------------------------------------
// Synapse update (depends on scatter's acc)
__global__ __launch_bounds__(256) void syn_kernel(
    const float4* __restrict__ acc,
    const float4* __restrict__ psc_rise,
    const float4* __restrict__ psc,
    const float4* __restrict__ syn_decay,
    const float4* __restrict__ psc_initial,
    float4* __restrict__ out_psc_rise,
    float4* __restrict__ out_psc,
    int n4)
{
    int j = blockIdx.x * 256 + threadIdx.x;
    if (j >= n4) return;
    float4 sd = syn_decay[j];
    float4 pr = psc_rise[j];
    float4 pi = psc_initial[j];
    float4 ac = acc[j];
    float4 ps = psc[j];
    float4 opr, ops;
    opr.x = sd.x * pr.x + ac.x * pi.x;
    opr.y = sd.y * pr.y + ac.y * pi.y;
    opr.z = sd.z * pr.z + ac.z * pi.z;
    opr.w = sd.w * pr.w + ac.w * pi.w;
    ops.x = ps.x * sd.x + sd.x * pr.x;
    ops.y = ps.y * sd.y + sd.y * pr.y;
    ops.z = ps.z * sd.z + sd.z * pr.z;
    ops.w = ps.w * sd.w + sd.w * pr.w;
    out_psc_rise[j] = opr;
    out_psc[j]      = ops;
}

} // namespace

extern "C" void kernel_launch(void* const* d_in, const int* in_sizes, int n_in,
                              void* d_out, int out_size, void* d_ws, size_t ws_size,
                              hipStream_t stream) {
    const float* inputs         = (const float*)d_in[0];
    const float* z_buf          = (const float*)d_in[1];
    const float* v              = (const float*)d_in[2];
    const float* r              = (const float*)d_in[3];
    const float* asc1           = (const float*)d_in[4];
    const float* asc2           = (const float*)d_in[5];
    const float* psc_rise       = (const float*)d_in[6];
    const float* psc            = (const float*)d_in[7];
    const float* rec_w          = (const float*)d_in[8];
    const int*   rec_idx        = (const int*)d_in[9];
    const float* v_th           = (const float*)d_in[10];
    const float* e_l            = (const float*)d_in[11];
    const float* v_reset        = (const float*)d_in[12];
    const float* g              = (const float*)d_in[13];
    const float* decay          = (const float*)d_in[14];
    const float* current_factor = (const float*)d_in[15];
    const float* t_ref          = (const float*)d_in[16];
    const float* k              = (const float*)d_in[17];
    const float* asc_amps       = (const float*)d_in[18];
    const float* syn_decay      = (const float*)d_in[19];
    const float* psc_initial    = (const float*)d_in[20];
    const float* voltage_scale  = (const float*)d_in[21];
    const float* voltage_offset = (const float*)d_in[22];

    float* out = (float*)d_out;
    float* acc = (float*)d_ws;                         // RN floats = 2 MB
    unsigned int* bits = (unsigned int*)(acc + RN);    // ZB_WORDS u32 = 31 KB

    // K1: all scatter-independent work in one dispatch
    pre_kernel<<<PRE_BLOCKS, 256, 0, stream>>>(
        z_buf, bits, (const float4*)inputs, (float4*)acc,
        v, r, asc1, asc2, psc, v_th, e_l, v_reset, g, decay,
        current_factor, t_ref, (const float2*)k, (const float2*)asc_amps,
        voltage_scale, voltage_offset, out);

    // K2: sparse recurrent scatter (dominant dispatch)
    scatter_kernel<<<1280, 256, 0, stream>>>(
        rec_w, (const int4*)rec_idx, bits, acc);

    // K3: synapse update
    syn_kernel<<<(RN / 4 + 255) / 256, 256, 0, stream>>>(
        (const float4*)acc, (const float4*)psc_rise, (const float4*)psc,
        (const float4*)syn_decay, (const float4*)psc_initial,
        (float4*)(out + 11 * N), (float4*)(out + 21 * N), RN / 4);
}